// Round 2
// baseline (246.058 us; speedup 1.0000x reference)
//
#include <hip/hip_runtime.h>
#include <math.h>

#define D        2048
#define E        64
#define NROWS    16384      // B*S = 4*4096
#define BM       32         // rows per block (K1)
#define BK       64         // k-tile
#define NT       256
#define KITERS   (D / BK)   // 32

// ---------------- K1: logits = (x * factor) @ W^T + 0.1*noise ----------------
// 512 blocks (2 per CU, 8 waves/CU), 256 threads, per-thread tile 2 rows x 4
// experts. Register-prefetch double buffering. Writes logits into the probs
// region of d_out; K2 converts in place.
__global__ __launch_bounds__(NT)
void gemm_kernel(const float* __restrict__ x,
                 const float* __restrict__ W,
                 const float* __restrict__ scond,
                 const float* __restrict__ noise,
                 const int* __restrict__ sidx,
                 float* __restrict__ logits_out)
{
    __shared__ float4 xs[BM][17];   // [row][k/4], 68-float row stride (pad)
    __shared__ float4 ws[BK][16];   // [k][e/4]

    const int tid = threadIdx.x;
    const int rowBase = blockIdx.x * BM;

    // reference order: router_input = x * (1 + sf*0.1), THEN gemm
    const float factor = 1.0f + 0.1f * scond[sidx[0]];

    // staging maps
    const int xk = tid & 15;    // k-chunk (float4)
    const int xr = tid >> 4;    // row slot: rows xr and xr+16
    const int we = tid & 63;    // expert row of W
    const int wk = tid >> 6;    // 16-k sub-chunk

    // compute maps
    const int eg = tid & 15;    // expert group: e0 = eg*4
    const int rg = tid >> 4;    // rows rg and rg+16 (16-apart -> 2-way LDS banks, free)
    const int e0 = eg << 2;

    float acc[2][4];
#pragma unroll
    for (int i = 0; i < 2; ++i)
#pragma unroll
        for (int j = 0; j < 4; ++j) acc[i][j] = 0.f;

    const float* xg = x + (size_t)rowBase * D;

    float4 xb[2], wb[4];
    // prefetch tile 0
#pragma unroll
    for (int i = 0; i < 2; ++i)
        xb[i] = *(const float4*)(xg + (xr + 16 * i) * D + (xk << 2));
#pragma unroll
    for (int j = 0; j < 4; ++j)
        wb[j] = *(const float4*)(W + we * D + (wk << 4) + (j << 2));

    for (int t = 0; t < KITERS; ++t) {
        // registers -> LDS (x scaled by factor here, matching ref rounding)
#pragma unroll
        for (int i = 0; i < 2; ++i) {
            float4 v = xb[i];
            v.x *= factor; v.y *= factor; v.z *= factor; v.w *= factor;
            xs[xr + 16 * i][xk] = v;
        }
        {
            float* wsf = (float*)ws;
#pragma unroll
            for (int j = 0; j < 4; ++j) {
                const int kk = (wk << 4) + (j << 2);
                wsf[(kk + 0) * E + we] = wb[j].x;
                wsf[(kk + 1) * E + we] = wb[j].y;
                wsf[(kk + 2) * E + we] = wb[j].z;
                wsf[(kk + 3) * E + we] = wb[j].w;
            }
        }
        __syncthreads();

        // prefetch tile t+1
        if (t + 1 < KITERS) {
            const int k0 = (t + 1) * BK;
#pragma unroll
            for (int i = 0; i < 2; ++i)
                xb[i] = *(const float4*)(xg + (xr + 16 * i) * D + k0 + (xk << 2));
#pragma unroll
            for (int j = 0; j < 4; ++j)
                wb[j] = *(const float4*)(W + we * D + k0 + (wk << 4) + (j << 2));
        }

        // compute: per k-group 6x ds_read_b128 + 32 FMA
#pragma unroll
        for (int kg = 0; kg < 16; ++kg) {
            float4 xv[2], wv[4];
#pragma unroll
            for (int i = 0; i < 2; ++i) xv[i] = xs[rg + 16 * i][kg];
#pragma unroll
            for (int c = 0; c < 4; ++c) wv[c] = ws[(kg << 2) + c][eg];
#pragma unroll
            for (int i = 0; i < 2; ++i) {
                const float x0 = xv[i].x, x1 = xv[i].y, x2 = xv[i].z, x3 = xv[i].w;
                acc[i][0] += x0 * wv[0].x; acc[i][1] += x0 * wv[0].y;
                acc[i][2] += x0 * wv[0].z; acc[i][3] += x0 * wv[0].w;
                acc[i][0] += x1 * wv[1].x; acc[i][1] += x1 * wv[1].y;
                acc[i][2] += x1 * wv[1].z; acc[i][3] += x1 * wv[1].w;
                acc[i][0] += x2 * wv[2].x; acc[i][1] += x2 * wv[2].y;
                acc[i][2] += x2 * wv[2].z; acc[i][3] += x2 * wv[2].w;
                acc[i][0] += x3 * wv[3].x; acc[i][1] += x3 * wv[3].y;
                acc[i][2] += x3 * wv[3].z; acc[i][3] += x3 * wv[3].w;
            }
        }
        __syncthreads();
    }

    // logits = acc + noise*0.1  (ref adds noise*NOISE_STD after the gemm)
#pragma unroll
    for (int i = 0; i < 2; ++i) {
        const int gRow = rowBase + rg + 16 * i;
        const float4 nz = *(const float4*)(noise + (size_t)gRow * E + e0);
        float4 o;
        o.x = acc[i][0] + 0.1f * nz.x;
        o.y = acc[i][1] + 0.1f * nz.y;
        o.z = acc[i][2] + 0.1f * nz.z;
        o.w = acc[i][3] + 0.1f * nz.w;
        *(float4*)(logits_out + (size_t)gRow * E + e0) = o;
    }
}

// ---------------- K2: softmax + top-2 + scatter, one wave per row ------------
// Reads logits from the probs region and overwrites in place (same thread,
// same address). 4096 blocks x 256 threads (4 rows/block).
__global__ __launch_bounds__(256)
void topk_kernel(float* __restrict__ probs,      // in: logits, out: probs
                 float* __restrict__ dispatch,
                 float* __restrict__ sel)
{
    const int lane = threadIdx.x & 63;
    const int wave = threadIdx.x >> 6;
    const int row  = blockIdx.x * 4 + wave;

    const float v = probs[(size_t)row * E + lane];

    // softmax (max-stabilized, matches jax.nn.softmax / np ref)
    float m = v;
#pragma unroll
    for (int off = 32; off > 0; off >>= 1)
        m = fmaxf(m, __shfl_xor(m, off, 64));
    const float p = expf(v - m);
    float s = p;
#pragma unroll
    for (int off = 32; off > 0; off >>= 1)
        s += __shfl_xor(s, off, 64);
    const float prob = p / s;
    probs[(size_t)row * E + lane] = prob;

    // top-1 (ties -> lower index, jax/np semantics)
    float bv = prob; int bi = lane;
#pragma unroll
    for (int off = 32; off > 0; off >>= 1) {
        const float ov = __shfl_xor(bv, off, 64);
        const int   oi = __shfl_xor(bi, off, 64);
        if (ov > bv || (ov == bv && oi < bi)) { bv = ov; bi = oi; }
    }
    // top-2: mask out argmax lane
    float cv = (lane == bi) ? -INFINITY : prob;
    int ci = lane;
#pragma unroll
    for (int off = 32; off > 0; off >>= 1) {
        const float ov = __shfl_xor(cv, off, 64);
        const int   oi = __shfl_xor(ci, off, 64);
        if (ov > cv || (ov == cv && oi < ci)) { cv = ov; ci = oi; }
    }

    const float sum2 = bv + cv;
    float dval = 0.f;
    if (lane == bi) dval = bv / sum2;
    if (lane == ci) dval = cv / sum2;
    dispatch[(size_t)row * E + lane] = dval;

    if (lane == 0) {
        float2 sv; sv.x = (float)bi; sv.y = (float)ci;
        *(float2*)(sel + (size_t)row * 2) = sv;
    }
}

extern "C" void kernel_launch(void* const* d_in, const int* in_sizes, int n_in,
                              void* d_out, int out_size, void* d_ws, size_t ws_size,
                              hipStream_t stream) {
    const float* x     = (const float*)d_in[0];
    const float* W     = (const float*)d_in[1];
    const float* scond = (const float*)d_in[2];
    const float* noise = (const float*)d_in[3];
    const int*   sidx  = (const int*)d_in[4];

    float* out      = (float*)d_out;
    float* dispatch = out;                              // [16384*64]
    float* probs    = out + (size_t)NROWS * E;          // [16384*64] (logits first)
    float* sel      = out + 2 * (size_t)NROWS * E;      // [16384*2] as float

    gemm_kernel<<<dim3(NROWS / BM), dim3(NT), 0, stream>>>(
        x, W, scond, noise, sidx, probs);
    topk_kernel<<<dim3(NROWS / 4), dim3(256), 0, stream>>>(
        probs, dispatch, sel);
}